// Round 10
// baseline (111.949 us; speedup 1.0000x reference)
//
#include <hip/hip_runtime.h>

// X: (8, 2048, 256) fp32; W1: (64,8); b1: (64); W2: (2,64); b2: (2)
// patches: p = 0..510, l = 4p..4p+7 ; out: (8, 511, 256, 2) fp32
#define L_DIM 2048
#define C_DIM 256
#define P_CNT 511
#define H_DIM 64

typedef float v2f __attribute__((ext_vector_type(2)));
static __device__ __forceinline__ v2f splat2(float s) { return (v2f){s, s}; }

static __device__ __forceinline__ float rl(unsigned v, int lane) {
    return __int_as_float(__builtin_amdgcn_readlane((int)v, lane));
}

// Packed tanh-form gelu via native exp2 (identical math to the R3/R8-passing kernels):
//   z = t*(k1 + k2*t^2), k1=-1.5957691216*log2e, k2=-0.0713548162*log2e
//   gelu(t) = t * rcp(1 + 2^z).  Inf-safe at both tails.
__device__ __forceinline__ v2f pk_gelu(v2f t) {
    v2f t2 = t * t;
    v2f z  = t * __builtin_elementwise_fma(t2, splat2(-0.10294324f),
                                           splat2(-2.3022038f));
    v2f e;
    e.x = __builtin_amdgcn_exp2f(z.x);
    e.y = __builtin_amdgcn_exp2f(z.y);
    v2f den = e + splat2(1.0f);
    v2f r;
    r.x = __builtin_amdgcn_rcpf(den.x);
    r.y = __builtin_amdgcn_rcpf(den.y);
    return t * r;
}

// thread = (b, channel, 2 patches packed into <2 x float> lanes)
// threads = 8 * 256 * 256 = 524288 = 2048 blocks * 256 -> 8 waves/SIMD
//
// Weight access: lane h (= tx & 63) holds W1[h][0..7], b1[h], W2[0][h], W2[1][h]
// in 11 VGPRs (loaded ONCE). The h-loop index is wave-uniform, so each iteration
// broadcasts its weights with v_readlane_b32 -> SGPR. The inner loop contains
// ZERO memory instructions: no s_load lgkm drains, no DS-pipe traffic, no vmcnt.
__global__ __launch_bounds__(256, 8) void offset_predictor_kernel(
    const float* __restrict__ X,
    const float* __restrict__ W1,
    const float* __restrict__ b1,
    const float* __restrict__ W2,
    const float* __restrict__ b2,
    float* __restrict__ out)
{
    const int tx   = threadIdx.x;
    const int lane = tx & 63;

    // Per-lane weight preload (once; tiny, L1/L2-cached)
    unsigned wreg[11];
    {
        const unsigned* W1u = (const unsigned*)W1;
        const unsigned* b1u = (const unsigned*)b1;
        const unsigned* W2u = (const unsigned*)W2;
#pragma unroll
        for (int j = 0; j < 8; ++j) wreg[j] = W1u[lane * 8 + j];
        wreg[8]  = b1u[lane];
        wreg[9]  = W2u[lane];            // W2[0][lane]
        wreg[10] = W2u[H_DIM + lane];    // W2[1][lane]
    }

    const int tid   = blockIdx.x * 256 + tx;
    const int c     = tid & 255;            // consecutive threads -> consecutive channels
    const int ptile = (tid >> 8) & 255;
    const int b     = tid >> 16;
    const int p0    = ptile * 2;

    // Patch-pair vectors: pv[j] = (X[4p0+j], X[4p0+4+j]) at channel c.
    const float* xb = X + (size_t)b * (L_DIM * C_DIM) + c;
    v2f pv[8];
#pragma unroll
    for (int j = 0; j < 8; ++j) {
        int l0 = 4 * p0 + j;                // <= 2047 always
        int l1 = l0 + 4;
        if (l1 > L_DIM - 1) l1 = L_DIM - 1; // only ptile=255's invalid second patch
        pv[j].x = xb[(size_t)l0 * C_DIM];
        pv[j].y = xb[(size_t)l1 * C_DIM];
    }

    const float bo0 = b2[0], bo1 = b2[1];   // s_load once, outside the loop
    v2f accA = splat2(bo0);                 // (o0 @ p0, o0 @ p0+1)
    v2f accB = splat2(bo1);                 // (o1 @ p0, o1 @ p0+1)

#pragma unroll 4
    for (int h = 0; h < H_DIM; ++h) {
        // 11 x v_readlane_b32: wave-uniform broadcast of row h's weights
        const float w0  = rl(wreg[0],  h);
        const float w1  = rl(wreg[1],  h);
        const float w2  = rl(wreg[2],  h);
        const float w3  = rl(wreg[3],  h);
        const float w4  = rl(wreg[4],  h);
        const float w5  = rl(wreg[5],  h);
        const float w6  = rl(wreg[6],  h);
        const float w7  = rl(wreg[7],  h);
        const float b1h = rl(wreg[8],  h);
        const float w2a = rl(wreg[9],  h);
        const float w2b = rl(wreg[10], h);

        v2f t = splat2(b1h);
        t = __builtin_elementwise_fma(pv[0], splat2(w0), t);
        t = __builtin_elementwise_fma(pv[1], splat2(w1), t);
        t = __builtin_elementwise_fma(pv[2], splat2(w2), t);
        t = __builtin_elementwise_fma(pv[3], splat2(w3), t);
        t = __builtin_elementwise_fma(pv[4], splat2(w4), t);
        t = __builtin_elementwise_fma(pv[5], splat2(w5), t);
        t = __builtin_elementwise_fma(pv[6], splat2(w6), t);
        t = __builtin_elementwise_fma(pv[7], splat2(w7), t);

        const v2f g = pk_gelu(t);

        accA = __builtin_elementwise_fma(g, splat2(w2a), accA);
        accB = __builtin_elementwise_fma(g, splat2(w2b), accB);
    }

    // out[((b*511 + p)*256 + c)*2 + o] : contiguous float2 per thread, coalesced across c
    float* ob = out + ((size_t)(b * P_CNT) * C_DIM + c) * 2;
    *(float2*)(ob + (size_t)p0 * (C_DIM * 2)) = make_float2(accA.x, accB.x);
    if (p0 + 1 < P_CNT)
        *(float2*)(ob + (size_t)(p0 + 1) * (C_DIM * 2)) = make_float2(accA.y, accB.y);
}

extern "C" void kernel_launch(void* const* d_in, const int* in_sizes, int n_in,
                              void* d_out, int out_size, void* d_ws, size_t ws_size,
                              hipStream_t stream) {
    const float* X  = (const float*)d_in[0];
    const float* W1 = (const float*)d_in[1];
    const float* b1 = (const float*)d_in[2];
    const float* W2 = (const float*)d_in[3];
    const float* b2 = (const float*)d_in[4];
    float* out = (float*)d_out;

    offset_predictor_kernel<<<2048, 256, 0, stream>>>(X, W1, b1, W2, b2, out);
}

// Round 11
// 94.323 us; speedup vs baseline: 1.1869x; 1.1869x over previous
//
#include <hip/hip_runtime.h>

// X: (8, 2048, 256) fp32; W1: (64,8); b1: (64); W2: (2,64); b2: (2)
// patches: p = 0..510, l = 4p..4p+7 ; out: (8, 511, 256, 2) fp32
#define L_DIM 2048
#define C_DIM 256
#define P_CNT 511
#define H_DIM 64

typedef float v2f __attribute__((ext_vector_type(2)));
static __device__ __forceinline__ v2f splat2(float s) { return (v2f){s, s}; }

// Packed tanh-form gelu via native exp2:
//   z = t*(k1 + k2*t^2), k1=-1.5957691216*log2e, k2=-0.0713548162*log2e
//   gelu(t) = t * rcp(1 + 2^z).  Inf-safe at both tails.
__device__ __forceinline__ v2f pk_gelu(v2f t) {
    v2f t2 = t * t;
    v2f z  = t * __builtin_elementwise_fma(t2, splat2(-0.10294324f),
                                           splat2(-2.3022038f));
    v2f e;
    e.x = __builtin_amdgcn_exp2f(z.x);
    e.y = __builtin_amdgcn_exp2f(z.y);
    v2f den = e + splat2(1.0f);
    v2f r;
    r.x = __builtin_amdgcn_rcpf(den.x);
    r.y = __builtin_amdgcn_rcpf(den.y);
    return t * r;
}

// thread = (b, channel, 2 patches packed into <2 x float> lanes)
// threads = 8 * 256 * 256 = 524288 = 2048 blocks * 256 -> 8 waves/SIMD
//
// h-loop is FULLY unrolled: the weight s_loads for all 64 rows become one flat
// stream the scheduler can batch/hoist arbitrarily far ahead (SGPR-limited
// software pipeline), instead of a per-body s_waitcnt lgkmcnt(0) convoy that
// stalls all 8 resident waves on the same cadence.
__global__ __launch_bounds__(256, 8) void offset_predictor_kernel(
    const float* __restrict__ X,
    const float* __restrict__ W1,
    const float* __restrict__ b1,
    const float* __restrict__ W2,
    const float* __restrict__ b2,
    float* __restrict__ out)
{
    const int tid   = blockIdx.x * 256 + threadIdx.x;
    const int c     = tid & 255;            // consecutive threads -> consecutive channels
    const int ptile = (tid >> 8) & 255;
    const int b     = tid >> 16;
    const int p0    = ptile * 2;

    // Patch-pair vectors: pv[j] = (X[4p0+j], X[4p0+4+j]) at channel c.
    const float* xb = X + (size_t)b * (L_DIM * C_DIM) + c;
    v2f pv[8];
#pragma unroll
    for (int j = 0; j < 8; ++j) {
        int l0 = 4 * p0 + j;                // <= 2047 always
        int l1 = l0 + 4;
        if (l1 > L_DIM - 1) l1 = L_DIM - 1; // only ptile=255's invalid second patch
        pv[j].x = xb[(size_t)l0 * C_DIM];
        pv[j].y = xb[(size_t)l1 * C_DIM];
    }

    const float bo0 = b2[0], bo1 = b2[1];
    v2f accA = splat2(bo0);                 // (o0 @ p0, o0 @ p0+1)
    v2f accB = splat2(bo1);                 // (o1 @ p0, o1 @ p0+1)

#pragma unroll
    for (int h = 0; h < H_DIM; ++h) {
        const float4 wa = *(const float4*)(W1 + h * 8);      // w1[h][0..3]
        const float4 wb = *(const float4*)(W1 + h * 8 + 4);  // w1[h][4..7]
        const float b1h = b1[h];
        const float w2a = W2[h];             // W2[0][h]
        const float w2b = W2[H_DIM + h];     // W2[1][h]

        v2f t = splat2(b1h);
        t = __builtin_elementwise_fma(pv[0], splat2(wa.x), t);
        t = __builtin_elementwise_fma(pv[1], splat2(wa.y), t);
        t = __builtin_elementwise_fma(pv[2], splat2(wa.z), t);
        t = __builtin_elementwise_fma(pv[3], splat2(wa.w), t);
        t = __builtin_elementwise_fma(pv[4], splat2(wb.x), t);
        t = __builtin_elementwise_fma(pv[5], splat2(wb.y), t);
        t = __builtin_elementwise_fma(pv[6], splat2(wb.z), t);
        t = __builtin_elementwise_fma(pv[7], splat2(wb.w), t);

        const v2f g = pk_gelu(t);

        accA = __builtin_elementwise_fma(g, splat2(w2a), accA);
        accB = __builtin_elementwise_fma(g, splat2(w2b), accB);
    }

    // out[((b*511 + p)*256 + c)*2 + o] : contiguous float2 per thread, coalesced across c
    float* ob = out + ((size_t)(b * P_CNT) * C_DIM + c) * 2;
    *(float2*)(ob + (size_t)p0 * (C_DIM * 2)) = make_float2(accA.x, accB.x);
    if (p0 + 1 < P_CNT)
        *(float2*)(ob + (size_t)(p0 + 1) * (C_DIM * 2)) = make_float2(accA.y, accB.y);
}

extern "C" void kernel_launch(void* const* d_in, const int* in_sizes, int n_in,
                              void* d_out, int out_size, void* d_ws, size_t ws_size,
                              hipStream_t stream) {
    const float* X  = (const float*)d_in[0];
    const float* W1 = (const float*)d_in[1];
    const float* b1 = (const float*)d_in[2];
    const float* W2 = (const float*)d_in[3];
    const float* b2 = (const float*)d_in[4];
    float* out = (float*)d_out;

    offset_predictor_kernel<<<2048, 256, 0, stream>>>(X, W1, b1, W2, b2, out);
}